// Round 2
// baseline (820.947 us; speedup 1.0000x reference)
//
#include <hip/hip_runtime.h>

// SSIM, B=16, C=1, H=W=1024, 11x11 separable Gaussian.
// 32x32 output tiles, ~24 KB LDS -> 5 blocks/CU (launch_bounds 256,5).
// Per tile:
//   phase 1 (x2 imgs): h-blur img rows [r0-10,r0+42) x cols [c0-10,c0+34) -> S
//                      (branchless: row-clamped dwordx4 loads + zero mask)
//   phase 2 (x2 imgs): v-blur S -> mu, fused with d = img - mu written to M,
//                      batched clamp-addressed img loads, global min/max fused
//   phase 2.5: mu(inner) = img - d  (registers, 4 px/thread)
//   stat passes x3: product + h-blur -> HP (in S), v-blur -> registers
//   combine: 1st-order Taylor in (C1,C2) -> 3 C-independent sums
// Block partials -> 64 hashed atomic slots; 64-thread finalize applies C1,C2.

#define IMG_H 1024
#define IMG_W 1024
#define TS    32          // output tile
#define MW    42          // TS + 10 (mu/d region)
#define MST   44          // LDS stride for M (mult of 4 -> float4 aligned)
#define HR    52          // TS + 20 (rows for horizontal pass)
#define HST   44          // S stride in h-blur layout (cols 0..41 valid)
#define HPW   32          // HP layout width
#define NST   11          // strips of 4 cols in phase 1 (44 cols, 42 valid)
#define NSLOT 64

__device__ __forceinline__ unsigned fkey(float f) {
  unsigned b = __float_as_uint(f);
  return (b & 0x80000000u) ? ~b : (b | 0x80000000u);
}
__device__ __forceinline__ float funkey(unsigned k) {
  return (k & 0x80000000u) ? __uint_as_float(k & 0x7FFFFFFFu)
                           : __uint_as_float(~k);
}

__global__ void ssim_init(unsigned* __restrict__ ws) {
  int t = threadIdx.x;
  ws[t * 8 + 0] = 0u;
  ws[t * 8 + 1] = 0u;
  ws[t * 8 + 2] = 0u;
  ws[t * 8 + 3] = 0xFFFFFFFFu;
  ws[t * 8 + 4] = 0u;
}

// one statistic: (product + h-blur) -> HP in S, then v-blur into dst regs.
// SIDX: 0 = d1*d1, 1 = d2*d2, 2 = d1*d2.
template <int SIDX>
__device__ __forceinline__ void stat_pass(int tid, const float g[11],
                                          float* __restrict__ S,
                                          const float* __restrict__ M1,
                                          const float* __restrict__ M2,
                                          int R0o, int c_own, float dst[4]) {
  __syncthreads();  // S free to overwrite, M ready
  #pragma unroll
  for (int k = 0; k < 2; ++k) {
    unsigned idx = (unsigned)tid + 256u * k;
    if (idx < (unsigned)(MW * 8)) {
      unsigned i = idx >> 3;
      int oc0 = (int)(idx & 7u) * 4;
      float a[16], b[16];
      if (SIDX != 1) {
        const float4* p = (const float4*)&M1[i * MST + oc0];  // 16B aligned
        #pragma unroll
        for (int q = 0; q < 4; ++q) {
          float4 t = p[q];
          a[4 * q] = t.x; a[4 * q + 1] = t.y; a[4 * q + 2] = t.z; a[4 * q + 3] = t.w;
        }
      }
      if (SIDX != 0) {
        const float4* p = (const float4*)&M2[i * MST + oc0];
        #pragma unroll
        for (int q = 0; q < 4; ++q) {
          float4 t = p[q];
          b[4 * q] = t.x; b[4 * q + 1] = t.y; b[4 * q + 2] = t.z; b[4 * q + 3] = t.w;
        }
      }
      float w[14];
      #pragma unroll
      for (int q = 0; q < 14; ++q)
        w[q] = (SIDX == 0) ? a[q] * a[q] : (SIDX == 1) ? b[q] * b[q] : a[q] * b[q];
      float4 o;
      float oq[4];
      #pragma unroll
      for (int q = 0; q < 4; ++q) {
        float acc = 0.f;
        #pragma unroll
        for (int j = 0; j < 11; ++j) acc = fmaf(g[j], w[q + j], acc);
        oq[q] = acc;
      }
      o.x = oq[0]; o.y = oq[1]; o.z = oq[2]; o.w = oq[3];
      *(float4*)&S[i * HPW + oc0] = o;
    }
  }
  __syncthreads();
  float win[14];
  #pragma unroll
  for (int j = 0; j < 14; ++j) win[j] = S[(R0o + j) * HPW + c_own];
  #pragma unroll
  for (int k = 0; k < 4; ++k) {
    float acc = 0.f;
    #pragma unroll
    for (int j = 0; j < 11; ++j) acc = fmaf(g[j], win[k + j], acc);
    dst[k] = acc;
  }
}

__global__ __launch_bounds__(256, 5)
void ssim_main(const float* __restrict__ img1, const float* __restrict__ img2,
               const float* __restrict__ kern, unsigned* __restrict__ ws) {
  __shared__ __align__(16) float S[HR * HST];   // 52*44: h-blur buf, reused as HP
  __shared__ __align__(16) float M1[MW * MST];  // d1
  __shared__ __align__(16) float M2[MW * MST];  // d2
  __shared__ float gsh[16];
  __shared__ float redbuf[4][8];

  const int tid = threadIdx.x;
  const int r0 = blockIdx.y * TS;
  const int c0 = blockIdx.x * TS;
  const size_t boff = (size_t)blockIdx.z * (IMG_H * IMG_W);
  const float* i1 = img1 + boff;
  const float* i2 = img2 + boff;

  if (tid < 11) gsh[tid] = kern[55 + tid] * rsqrtf(kern[60]);
  __syncthreads();
  float g[11];
  #pragma unroll
  for (int j = 0; j < 11; ++j) g[j] = gsh[j];

  float vmin = 1e30f, vmax = -1e30f;

  // ---- mu + d for both images ----
  #pragma unroll 1
  for (int im = 0; im < 2; ++im) {
    const float* img = im ? i2 : i1;
    float* M = im ? M2 : M1;
    if (im) __syncthreads();  // S reuse (phase 2 of im=0 read S)

    // phase 1: horizontal blur into S. Branchless interior: row clamp + mask,
    // 4x float4 loads (16B aligned since (c0+cc0-12) % 4 == 0).
    #pragma unroll
    for (int k = 0; k < 3; ++k) {
      unsigned idx = (unsigned)tid + 256u * k;
      if (idx < (unsigned)(HR * NST)) {
        unsigned rr = idx / NST;
        unsigned strip = idx - rr * NST;
        int cc0 = (int)strip * 4;
        int gr = r0 - 10 + (int)rr;
        int grc = min(max(gr, 0), IMG_H - 1);
        float rowmask = (gr == grc) ? 1.f : 0.f;
        const float* rowp = img + (size_t)grc * IMG_W;
        int gcb = c0 + cc0 - 10;  // global col of w[0]
        float w16[16];
        if (gcb - 2 >= 0 && gcb + 14 <= IMG_W) {
          const float4* p4 = (const float4*)(rowp + gcb - 2);
          #pragma unroll
          for (int q = 0; q < 4; ++q) {
            float4 t = p4[q];
            w16[4 * q] = t.x; w16[4 * q + 1] = t.y;
            w16[4 * q + 2] = t.z; w16[4 * q + 3] = t.w;
          }
        } else {
          #pragma unroll
          for (int q = 0; q < 16; ++q) {
            int gc = gcb - 2 + q;
            w16[q] = (gc >= 0 && gc < IMG_W) ? rowp[gc] : 0.f;
          }
        }
        #pragma unroll
        for (int q = 0; q < 4; ++q) {
          float acc = 0.f;
          #pragma unroll
          for (int j = 0; j < 11; ++j) acc = fmaf(g[j], w16[q + j + 2], acc);
          S[rr * HST + cc0 + q] = acc * rowmask;
        }
      }
    }
    __syncthreads();

    // phase 2: v-blur -> mu, fused d = img - mu into M, fused min/max.
    // 252 items: (row-chunk rbv<6 of 8 rows) x (col cc<42).
    if (tid < 6 * MW) {
      unsigned rbv = (unsigned)tid / MW;
      unsigned cc = (unsigned)tid - rbv * MW;
      int R0v = (int)rbv * 8;
      float win[18];
      #pragma unroll
      for (int j = 0; j < 18; ++j) {
        int rr = R0v + j;
        win[j] = (rr < HR) ? S[rr * HST + cc] : 0.f;
      }
      int gc = c0 - 5 + (int)cc;
      int gcc = min(max(gc, 0), IMG_W - 1);
      // batched, clamp-addressed loads (all issued before use)
      float v[8];
      #pragma unroll
      for (int q = 0; q < 8; ++q) {
        int gr = r0 - 5 + R0v + q;
        int grc = min(max(gr, 0), IMG_H - 1);
        v[q] = img[(size_t)grc * IMG_W + gcc];
      }
      #pragma unroll
      for (int q = 0; q < 8; ++q) {
        int r2 = R0v + q;
        if (r2 < MW) {
          float acc = 0.f;
          #pragma unroll
          for (int j = 0; j < 11; ++j) acc = fmaf(g[j], win[q + j], acc);
          int gr = r0 - 5 + r2;
          bool in = (gr >= 0) && (gr < IMG_H) && (gc >= 0) && (gc < IMG_W);
          vmin = fminf(vmin, in ? v[q] : 1e30f);
          vmax = fmaxf(vmax, in ? v[q] : -1e30f);
          M[r2 * MST + cc] = in ? (v[q] - acc) : 0.f;
        }
      }
    }
  }
  __syncthreads();  // M2 ready; S free

  // phase 2.5: inner mu in registers: mu = img - d (img reads are L1-hot)
  const int c_own = tid & 31;
  const int R0o = (tid >> 5) * 4;
  float mu1r[4], mu2r[4];
  #pragma unroll
  for (int k = 0; k < 4; ++k) {
    size_t off = (size_t)(r0 + R0o + k) * IMG_W + (c0 + c_own);
    mu1r[k] = i1[off] - M1[(R0o + k + 5) * MST + c_own + 5];
    mu2r[k] = i2[off] - M2[(R0o + k + 5) * MST + c_own + 5];
  }

  // stat passes
  float s11r[4], s22r[4], s12r[4];
  stat_pass<0>(tid, g, S, M1, M2, R0o, c_own, s11r);
  stat_pass<1>(tid, g, S, M1, M2, R0o, c_own, s22r);
  stat_pass<2>(tid, g, S, M1, M2, R0o, c_own, s12r);

  // combine: ssim ~= S0*B0 + C1*(S0*B') + C2*(B0*S')
  float acc0 = 0.f, aC1 = 0.f, aC2 = 0.f;
  #pragma unroll
  for (int k = 0; k < 4; ++k) {
    float s1 = s11r[k] + 1.f;
    float s2 = s22r[k] + 1.f;
    float s12v = s12r[k] + 1.f;
    float m1 = mu1r[k], m2 = mu2r[k];
    float a = 2.f * s12v;
    float b = s1 + s2;
    float rb = __builtin_amdgcn_rcpf(b);
    float S0 = a * rb;
    float Sp = (b - a) * rb * rb;
    float m12 = fmaf(m1, m2, 1.f);
    float nb = 2.f * m12;
    float N1 = nb * nb;
    float ms = fmaf(m1, m1, fmaf(m2, m2, 2.f));
    float D1 = ms * ms;
    float rD = __builtin_amdgcn_rcpf(D1);
    float B0 = N1 * rD;
    float Bp = (D1 - N1) * rD * rD;
    acc0 = fmaf(S0, B0, acc0);
    aC1 = fmaf(S0, Bp, aC1);
    aC2 = fmaf(B0, Sp, aC2);
  }

  // block reduction
  #pragma unroll
  for (int off = 32; off > 0; off >>= 1) {
    acc0 += __shfl_down(acc0, off);
    aC1 += __shfl_down(aC1, off);
    aC2 += __shfl_down(aC2, off);
    vmin = fminf(vmin, __shfl_down(vmin, off));
    vmax = fmaxf(vmax, __shfl_down(vmax, off));
  }
  const int wv = tid >> 6, ln = tid & 63;
  if (ln == 0) {
    redbuf[wv][0] = acc0; redbuf[wv][1] = aC1; redbuf[wv][2] = aC2;
    redbuf[wv][3] = vmin; redbuf[wv][4] = vmax;
  }
  __syncthreads();
  if (tid == 0) {
    float t0 = 0.f, t1 = 0.f, t2 = 0.f, mn = 1e30f, mx = -1e30f;
    #pragma unroll
    for (int w2 = 0; w2 < 4; ++w2) {
      t0 += redbuf[w2][0]; t1 += redbuf[w2][1]; t2 += redbuf[w2][2];
      mn = fminf(mn, redbuf[w2][3]); mx = fmaxf(mx, redbuf[w2][4]);
    }
    unsigned slot = (blockIdx.x + blockIdx.y * 32u + blockIdx.z * 7u) & (NSLOT - 1);
    float* wsF = (float*)ws;
    atomicAdd(&wsF[slot * 8 + 0], t0);
    atomicAdd(&wsF[slot * 8 + 1], t1);
    atomicAdd(&wsF[slot * 8 + 2], t2);
    atomicMin(&ws[slot * 8 + 3], fkey(mn));
    atomicMax(&ws[slot * 8 + 4], fkey(mx));
  }
}

__global__ void ssim_final(const unsigned* __restrict__ ws, float* __restrict__ out) {
  const int t = threadIdx.x;  // 64 threads, one wave
  const float* wsF = (const float*)ws;
  float t0 = wsF[t * 8 + 0], t1 = wsF[t * 8 + 1], t2 = wsF[t * 8 + 2];
  unsigned kmn = ws[t * 8 + 3], kmx = ws[t * 8 + 4];
  #pragma unroll
  for (int off = 32; off > 0; off >>= 1) {
    t0 += __shfl_down(t0, off);
    t1 += __shfl_down(t1, off);
    t2 += __shfl_down(t2, off);
    kmn = min(kmn, (unsigned)__shfl_down((int)kmn, off));
    kmx = max(kmx, (unsigned)__shfl_down((int)kmx, off));
  }
  if (t == 0) {
    float mn = funkey(kmn), mx = funkey(kmx);
    float vr = mx - mn + 1e-5f;
    float c1 = 0.01f * vr; c1 *= c1;
    float c2 = 0.03f * vr; c2 *= c2;
    float mean = (t0 + c1 * t1 + c2 * t2) * (1.0f / 16777216.0f);
    out[0] = 1.f - mean;
  }
}

extern "C" void kernel_launch(void* const* d_in, const int* in_sizes, int n_in,
                              void* d_out, int out_size, void* d_ws, size_t ws_size,
                              hipStream_t stream) {
  const float* img1 = (const float*)d_in[0];
  const float* img2 = (const float*)d_in[1];
  const float* kern = (const float*)d_in[2];
  unsigned* ws = (unsigned*)d_ws;
  float* out = (float*)d_out;
  (void)in_sizes; (void)n_in; (void)out_size; (void)ws_size;

  hipLaunchKernelGGL(ssim_init, dim3(1), dim3(NSLOT), 0, stream, ws);
  hipLaunchKernelGGL(ssim_main, dim3(IMG_W / TS, IMG_H / TS, 16), dim3(256), 0,
                     stream, img1, img2, kern, ws);
  hipLaunchKernelGGL(ssim_final, dim3(1), dim3(NSLOT), 0, stream, ws, out);
}

// Round 3
// 563.175 us; speedup vs baseline: 1.4577x; 1.4577x over previous
//
#include <hip/hip_runtime.h>

// SSIM, B=16, C=1, H=W=1024, 11x11 separable Gaussian.
// 32x32 output tiles, ~24 KB LDS. launch_bounds(256,4): 128-VGPR cap ->
// no scratch spills (R2's (256,5) cap caused 1.6 GB of spill traffic),
// 4 blocks/CU co-resident.
// Per tile:
//   phase 1 (x2 imgs): h-blur img rows [r0-10,r0+42) x cols [c0-10,c0+34) -> S
//                      (branchless: row-clamped dwordx4 loads + zero mask)
//   phase 2 (x2 imgs): v-blur S -> mu, fused with d = img - mu written to M,
//                      batched clamp-addressed img loads, global min/max fused
//   phase 2.5: mu(inner) = img - d  (registers, 4 px/thread)
//   stat passes x3: product + h-blur -> HP (in S), v-blur -> registers
//   combine: 1st-order Taylor in (C1,C2) -> 3 C-independent sums
// Block partials -> 64 hashed atomic slots; 64-thread finalize applies C1,C2.

#define IMG_H 1024
#define IMG_W 1024
#define TS    32          // output tile
#define MW    42          // TS + 10 (mu/d region)
#define MST   44          // LDS stride for M (mult of 4 -> float4 aligned)
#define HR    52          // TS + 20 (rows for horizontal pass)
#define HST   44          // S stride in h-blur layout (cols 0..41 valid)
#define HPW   32          // HP layout width
#define NST   11          // strips of 4 cols in phase 1 (44 cols, 42 valid)
#define NSLOT 64

__device__ __forceinline__ unsigned fkey(float f) {
  unsigned b = __float_as_uint(f);
  return (b & 0x80000000u) ? ~b : (b | 0x80000000u);
}
__device__ __forceinline__ float funkey(unsigned k) {
  return (k & 0x80000000u) ? __uint_as_float(k & 0x7FFFFFFFu)
                           : __uint_as_float(~k);
}

__global__ void ssim_init(unsigned* __restrict__ ws) {
  int t = threadIdx.x;
  ws[t * 8 + 0] = 0u;
  ws[t * 8 + 1] = 0u;
  ws[t * 8 + 2] = 0u;
  ws[t * 8 + 3] = 0xFFFFFFFFu;
  ws[t * 8 + 4] = 0u;
}

// one statistic: (product + h-blur) -> HP in S, then v-blur into dst regs.
// SIDX: 0 = d1*d1, 1 = d2*d2, 2 = d1*d2.
template <int SIDX>
__device__ __forceinline__ void stat_pass(int tid, const float g[11],
                                          float* __restrict__ S,
                                          const float* __restrict__ M1,
                                          const float* __restrict__ M2,
                                          int R0o, int c_own, float dst[4]) {
  __syncthreads();  // S free to overwrite, M ready
  #pragma unroll
  for (int k = 0; k < 2; ++k) {
    unsigned idx = (unsigned)tid + 256u * k;
    if (idx < (unsigned)(MW * 8)) {
      unsigned i = idx >> 3;
      int oc0 = (int)(idx & 7u) * 4;
      float a[16], b[16];
      if (SIDX != 1) {
        const float4* p = (const float4*)&M1[i * MST + oc0];  // 16B aligned
        #pragma unroll
        for (int q = 0; q < 4; ++q) {
          float4 t = p[q];
          a[4 * q] = t.x; a[4 * q + 1] = t.y; a[4 * q + 2] = t.z; a[4 * q + 3] = t.w;
        }
      }
      if (SIDX != 0) {
        const float4* p = (const float4*)&M2[i * MST + oc0];
        #pragma unroll
        for (int q = 0; q < 4; ++q) {
          float4 t = p[q];
          b[4 * q] = t.x; b[4 * q + 1] = t.y; b[4 * q + 2] = t.z; b[4 * q + 3] = t.w;
        }
      }
      float w[14];
      #pragma unroll
      for (int q = 0; q < 14; ++q)
        w[q] = (SIDX == 0) ? a[q] * a[q] : (SIDX == 1) ? b[q] * b[q] : a[q] * b[q];
      float4 o;
      float oq[4];
      #pragma unroll
      for (int q = 0; q < 4; ++q) {
        float acc = 0.f;
        #pragma unroll
        for (int j = 0; j < 11; ++j) acc = fmaf(g[j], w[q + j], acc);
        oq[q] = acc;
      }
      o.x = oq[0]; o.y = oq[1]; o.z = oq[2]; o.w = oq[3];
      *(float4*)&S[i * HPW + oc0] = o;
    }
  }
  __syncthreads();
  float win[14];
  #pragma unroll
  for (int j = 0; j < 14; ++j) win[j] = S[(R0o + j) * HPW + c_own];
  #pragma unroll
  for (int k = 0; k < 4; ++k) {
    float acc = 0.f;
    #pragma unroll
    for (int j = 0; j < 11; ++j) acc = fmaf(g[j], win[k + j], acc);
    dst[k] = acc;
  }
}

__global__ __launch_bounds__(256, 4)
void ssim_main(const float* __restrict__ img1, const float* __restrict__ img2,
               const float* __restrict__ kern, unsigned* __restrict__ ws) {
  __shared__ __align__(16) float S[HR * HST];   // 52*44: h-blur buf, reused as HP
  __shared__ __align__(16) float M1[MW * MST];  // d1
  __shared__ __align__(16) float M2[MW * MST];  // d2
  __shared__ float gsh[16];
  __shared__ float redbuf[4][8];

  const int tid = threadIdx.x;
  const int r0 = blockIdx.y * TS;
  const int c0 = blockIdx.x * TS;
  const size_t boff = (size_t)blockIdx.z * (IMG_H * IMG_W);
  const float* i1 = img1 + boff;
  const float* i2 = img2 + boff;

  if (tid < 11) gsh[tid] = kern[55 + tid] * rsqrtf(kern[60]);
  __syncthreads();
  float g[11];
  #pragma unroll
  for (int j = 0; j < 11; ++j) g[j] = gsh[j];

  float vmin = 1e30f, vmax = -1e30f;

  // ---- mu + d for both images ----
  #pragma unroll 1
  for (int im = 0; im < 2; ++im) {
    const float* img = im ? i2 : i1;
    float* M = im ? M2 : M1;
    if (im) __syncthreads();  // S reuse (phase 2 of im=0 read S)

    // phase 1: horizontal blur into S. Branchless interior: row clamp + mask,
    // 4x float4 loads (16B aligned since (c0+cc0-12) % 4 == 0).
    #pragma unroll
    for (int k = 0; k < 3; ++k) {
      unsigned idx = (unsigned)tid + 256u * k;
      if (idx < (unsigned)(HR * NST)) {
        unsigned rr = idx / NST;
        unsigned strip = idx - rr * NST;
        int cc0 = (int)strip * 4;
        int gr = r0 - 10 + (int)rr;
        int grc = min(max(gr, 0), IMG_H - 1);
        float rowmask = (gr == grc) ? 1.f : 0.f;
        const float* rowp = img + (size_t)grc * IMG_W;
        int gcb = c0 + cc0 - 10;  // global col of w[0]
        float w16[16];
        if (gcb - 2 >= 0 && gcb + 14 <= IMG_W) {
          const float4* p4 = (const float4*)(rowp + gcb - 2);
          #pragma unroll
          for (int q = 0; q < 4; ++q) {
            float4 t = p4[q];
            w16[4 * q] = t.x; w16[4 * q + 1] = t.y;
            w16[4 * q + 2] = t.z; w16[4 * q + 3] = t.w;
          }
        } else {
          #pragma unroll
          for (int q = 0; q < 16; ++q) {
            int gc = gcb - 2 + q;
            w16[q] = (gc >= 0 && gc < IMG_W) ? rowp[gc] : 0.f;
          }
        }
        #pragma unroll
        for (int q = 0; q < 4; ++q) {
          float acc = 0.f;
          #pragma unroll
          for (int j = 0; j < 11; ++j) acc = fmaf(g[j], w16[q + j + 2], acc);
          S[rr * HST + cc0 + q] = acc * rowmask;
        }
      }
    }
    __syncthreads();

    // phase 2: v-blur -> mu, fused d = img - mu into M, fused min/max.
    // 252 items: (row-chunk rbv<6 of 8 rows) x (col cc<42).
    if (tid < 6 * MW) {
      unsigned rbv = (unsigned)tid / MW;
      unsigned cc = (unsigned)tid - rbv * MW;
      int R0v = (int)rbv * 8;
      float win[18];
      #pragma unroll
      for (int j = 0; j < 18; ++j) {
        int rr = R0v + j;
        win[j] = (rr < HR) ? S[rr * HST + cc] : 0.f;
      }
      int gc = c0 - 5 + (int)cc;
      int gcc = min(max(gc, 0), IMG_W - 1);
      // batched, clamp-addressed loads (all issued before use)
      float v[8];
      #pragma unroll
      for (int q = 0; q < 8; ++q) {
        int gr = r0 - 5 + R0v + q;
        int grc = min(max(gr, 0), IMG_H - 1);
        v[q] = img[(size_t)grc * IMG_W + gcc];
      }
      #pragma unroll
      for (int q = 0; q < 8; ++q) {
        int r2 = R0v + q;
        if (r2 < MW) {
          float acc = 0.f;
          #pragma unroll
          for (int j = 0; j < 11; ++j) acc = fmaf(g[j], win[q + j], acc);
          int gr = r0 - 5 + r2;
          bool in = (gr >= 0) && (gr < IMG_H) && (gc >= 0) && (gc < IMG_W);
          vmin = fminf(vmin, in ? v[q] : 1e30f);
          vmax = fmaxf(vmax, in ? v[q] : -1e30f);
          M[r2 * MST + cc] = in ? (v[q] - acc) : 0.f;
        }
      }
    }
  }
  __syncthreads();  // M2 ready; S free

  // phase 2.5: inner mu in registers: mu = img - d (img reads are L1-hot)
  const int c_own = tid & 31;
  const int R0o = (tid >> 5) * 4;
  float mu1r[4], mu2r[4];
  #pragma unroll
  for (int k = 0; k < 4; ++k) {
    size_t off = (size_t)(r0 + R0o + k) * IMG_W + (c0 + c_own);
    mu1r[k] = i1[off] - M1[(R0o + k + 5) * MST + c_own + 5];
    mu2r[k] = i2[off] - M2[(R0o + k + 5) * MST + c_own + 5];
  }

  // stat passes
  float s11r[4], s22r[4], s12r[4];
  stat_pass<0>(tid, g, S, M1, M2, R0o, c_own, s11r);
  stat_pass<1>(tid, g, S, M1, M2, R0o, c_own, s22r);
  stat_pass<2>(tid, g, S, M1, M2, R0o, c_own, s12r);

  // combine: ssim ~= S0*B0 + C1*(S0*B') + C2*(B0*S')
  float acc0 = 0.f, aC1 = 0.f, aC2 = 0.f;
  #pragma unroll
  for (int k = 0; k < 4; ++k) {
    float s1 = s11r[k] + 1.f;
    float s2 = s22r[k] + 1.f;
    float s12v = s12r[k] + 1.f;
    float m1 = mu1r[k], m2 = mu2r[k];
    float a = 2.f * s12v;
    float b = s1 + s2;
    float rb = __builtin_amdgcn_rcpf(b);
    float S0 = a * rb;
    float Sp = (b - a) * rb * rb;
    float m12 = fmaf(m1, m2, 1.f);
    float nb = 2.f * m12;
    float N1 = nb * nb;
    float ms = fmaf(m1, m1, fmaf(m2, m2, 2.f));
    float D1 = ms * ms;
    float rD = __builtin_amdgcn_rcpf(D1);
    float B0 = N1 * rD;
    float Bp = (D1 - N1) * rD * rD;
    acc0 = fmaf(S0, B0, acc0);
    aC1 = fmaf(S0, Bp, aC1);
    aC2 = fmaf(B0, Sp, aC2);
  }

  // block reduction
  #pragma unroll
  for (int off = 32; off > 0; off >>= 1) {
    acc0 += __shfl_down(acc0, off);
    aC1 += __shfl_down(aC1, off);
    aC2 += __shfl_down(aC2, off);
    vmin = fminf(vmin, __shfl_down(vmin, off));
    vmax = fmaxf(vmax, __shfl_down(vmax, off));
  }
  const int wv = tid >> 6, ln = tid & 63;
  if (ln == 0) {
    redbuf[wv][0] = acc0; redbuf[wv][1] = aC1; redbuf[wv][2] = aC2;
    redbuf[wv][3] = vmin; redbuf[wv][4] = vmax;
  }
  __syncthreads();
  if (tid == 0) {
    float t0 = 0.f, t1 = 0.f, t2 = 0.f, mn = 1e30f, mx = -1e30f;
    #pragma unroll
    for (int w2 = 0; w2 < 4; ++w2) {
      t0 += redbuf[w2][0]; t1 += redbuf[w2][1]; t2 += redbuf[w2][2];
      mn = fminf(mn, redbuf[w2][3]); mx = fmaxf(mx, redbuf[w2][4]);
    }
    unsigned slot = (blockIdx.x + blockIdx.y * 32u + blockIdx.z * 7u) & (NSLOT - 1);
    float* wsF = (float*)ws;
    atomicAdd(&wsF[slot * 8 + 0], t0);
    atomicAdd(&wsF[slot * 8 + 1], t1);
    atomicAdd(&wsF[slot * 8 + 2], t2);
    atomicMin(&ws[slot * 8 + 3], fkey(mn));
    atomicMax(&ws[slot * 8 + 4], fkey(mx));
  }
}

__global__ void ssim_final(const unsigned* __restrict__ ws, float* __restrict__ out) {
  const int t = threadIdx.x;  // 64 threads, one wave
  const float* wsF = (const float*)ws;
  float t0 = wsF[t * 8 + 0], t1 = wsF[t * 8 + 1], t2 = wsF[t * 8 + 2];
  unsigned kmn = ws[t * 8 + 3], kmx = ws[t * 8 + 4];
  #pragma unroll
  for (int off = 32; off > 0; off >>= 1) {
    t0 += __shfl_down(t0, off);
    t1 += __shfl_down(t1, off);
    t2 += __shfl_down(t2, off);
    kmn = min(kmn, (unsigned)__shfl_down((int)kmn, off));
    kmx = max(kmx, (unsigned)__shfl_down((int)kmx, off));
  }
  if (t == 0) {
    float mn = funkey(kmn), mx = funkey(kmx);
    float vr = mx - mn + 1e-5f;
    float c1 = 0.01f * vr; c1 *= c1;
    float c2 = 0.03f * vr; c2 *= c2;
    float mean = (t0 + c1 * t1 + c2 * t2) * (1.0f / 16777216.0f);
    out[0] = 1.f - mean;
  }
}

extern "C" void kernel_launch(void* const* d_in, const int* in_sizes, int n_in,
                              void* d_out, int out_size, void* d_ws, size_t ws_size,
                              hipStream_t stream) {
  const float* img1 = (const float*)d_in[0];
  const float* img2 = (const float*)d_in[1];
  const float* kern = (const float*)d_in[2];
  unsigned* ws = (unsigned*)d_ws;
  float* out = (float*)d_out;
  (void)in_sizes; (void)n_in; (void)out_size; (void)ws_size;

  hipLaunchKernelGGL(ssim_init, dim3(1), dim3(NSLOT), 0, stream, ws);
  hipLaunchKernelGGL(ssim_main, dim3(IMG_W / TS, IMG_H / TS, 16), dim3(256), 0,
                     stream, img1, img2, kern, ws);
  hipLaunchKernelGGL(ssim_final, dim3(1), dim3(NSLOT), 0, stream, ws, out);
}

// Round 4
// 460.435 us; speedup vs baseline: 1.7830x; 1.2231x over previous
//
#include <hip/hip_runtime.h>

// SSIM, B=16, C=1, H=W=1024, 11x11 separable Gaussian.
// 32x32 output tiles, ~31 KB LDS.
// NOTE (R2/R3 post-mortem): __launch_bounds__(256,N) on this toolchain caps
// the VGPR budget at ~256/N -> N=4/5 forced massive scratch spilling
// (756MB-1.6GB of HBM write traffic). N=2 (cap 128) is spill-free (R1: 88
// VGPRs); runtime occupancy is set by VGPR/LDS, not by the hint.
// Per tile:
//   phase 1 (x2 imgs): h-blur img (52 rows x 42 cols) -> S  (row-clamped
//                      dwordx4 global loads, zero mask, float4 LDS stores)
//   phase 2 (x2 imgs): v-blur S -> mu, fused d = img - mu -> M1/M2,
//                      batched clamp-addressed img loads, min/max fused
//   phase 2.5: mu(inner) = img - d  (registers, 4 px/thread)
//   merged stat pass: d1d1/d2d2/d1d2 h-blur -> 3 HP planes in S (one barrier
//                     pair instead of three), v-blur -> registers
//   combine: 1st-order Taylor in (C1,C2) -> 3 C-independent sums
// Block partials -> 64 hashed atomic slots (min via max(fkey(-v)) so the
// workspace zero-memset is a valid init); 64-thread finalize applies C1,C2.

#define IMG_H 1024
#define IMG_W 1024
#define TS    32          // output tile
#define MW    42          // TS + 10 (mu/d region)
#define MST   44          // LDS stride for M (mult of 4 -> float4 aligned)
#define HR    52          // TS + 20 (rows for horizontal pass)
#define HST   44          // S stride in h-blur layout (cols 0..41 valid)
#define HPW   32          // HP plane width
#define HPP   (MW * HPW)  // HP plane size (1344 floats)
#define NST   11          // strips of 4 cols in phase 1 (44 cols, 42 valid)
#define NSLOT 64
#define SSZ   (3 * HPP)   // 4032 floats >= HR*HST = 2288

__device__ __forceinline__ unsigned fkey(float f) {
  unsigned b = __float_as_uint(f);
  return (b & 0x80000000u) ? ~b : (b | 0x80000000u);
}
__device__ __forceinline__ float funkey(unsigned k) {
  return (k & 0x80000000u) ? __uint_as_float(k & 0x7FFFFFFFu)
                           : __uint_as_float(~k);
}

__global__ __launch_bounds__(256, 2)
void ssim_main(const float* __restrict__ img1, const float* __restrict__ img2,
               const float* __restrict__ kern, unsigned* __restrict__ ws) {
  __shared__ __align__(16) float S[SSZ];        // h-blur buf / 3 HP planes
  __shared__ __align__(16) float M1[MW * MST];  // d1
  __shared__ __align__(16) float M2[MW * MST];  // d2
  __shared__ float gsh[16];
  __shared__ float redbuf[4][8];

  const int tid = threadIdx.x;
  const int r0 = blockIdx.y * TS;
  const int c0 = blockIdx.x * TS;
  const size_t boff = (size_t)blockIdx.z * (IMG_H * IMG_W);
  const float* i1 = img1 + boff;
  const float* i2 = img2 + boff;

  if (tid < 11) gsh[tid] = kern[55 + tid] * rsqrtf(kern[60]);
  __syncthreads();
  float g[11];
  #pragma unroll
  for (int j = 0; j < 11; ++j) g[j] = gsh[j];

  float vmin = 1e30f, vmax = -1e30f;

  // ---- mu + d for both images ----
  #pragma unroll 1
  for (int im = 0; im < 2; ++im) {
    const float* img = im ? i2 : i1;
    float* M = im ? M2 : M1;
    if (im) __syncthreads();  // S reuse (phase 2 of im=0 read S)

    // phase 1: horizontal blur into S (float4 stores; row clamp + zero mask).
    #pragma unroll
    for (int k = 0; k < 3; ++k) {
      unsigned idx = (unsigned)tid + 256u * k;
      if (idx < (unsigned)(HR * NST)) {
        unsigned rr = idx / NST;
        unsigned strip = idx - rr * NST;
        int cc0 = (int)strip * 4;
        int gr = r0 - 10 + (int)rr;
        int grc = min(max(gr, 0), IMG_H - 1);
        float rowmask = (gr == grc) ? 1.f : 0.f;
        const float* rowp = img + (size_t)grc * IMG_W;
        int gcb = c0 + cc0 - 10;  // global col of conv tap 0 for out col cc0
        float w16[16];            // cols gcb-2 .. gcb+13 (gcb-2 % 4 == 0)
        if (gcb - 2 >= 0 && gcb + 14 <= IMG_W) {
          const float4* p4 = (const float4*)(rowp + gcb - 2);
          #pragma unroll
          for (int q = 0; q < 4; ++q) {
            float4 t = p4[q];
            w16[4 * q] = t.x; w16[4 * q + 1] = t.y;
            w16[4 * q + 2] = t.z; w16[4 * q + 3] = t.w;
          }
        } else {
          #pragma unroll
          for (int q = 0; q < 16; ++q) {
            int gc = gcb - 2 + q;
            w16[q] = (gc >= 0 && gc < IMG_W) ? rowp[gc] : 0.f;
          }
        }
        float4 o;
        float oq[4];
        #pragma unroll
        for (int q = 0; q < 4; ++q) {
          float acc = 0.f;
          #pragma unroll
          for (int j = 0; j < 11; ++j) acc = fmaf(g[j], w16[q + j + 2], acc);
          oq[q] = acc * rowmask;
        }
        o.x = oq[0]; o.y = oq[1]; o.z = oq[2]; o.w = oq[3];
        *(float4*)&S[rr * HST + cc0] = o;
      }
    }
    __syncthreads();

    // phase 2: v-blur -> mu, fused d = img - mu into M, fused min/max.
    if (tid < 6 * MW) {
      unsigned rbv = (unsigned)tid / MW;
      unsigned cc = (unsigned)tid - rbv * MW;
      int R0v = (int)rbv * 8;
      float win[18];
      #pragma unroll
      for (int j = 0; j < 18; ++j) {
        int rr = R0v + j;
        win[j] = (rr < HR) ? S[rr * HST + cc] : 0.f;
      }
      int gc = c0 - 5 + (int)cc;
      int gcc = min(max(gc, 0), IMG_W - 1);
      float v[8];
      #pragma unroll
      for (int q = 0; q < 8; ++q) {
        int gr = r0 - 5 + R0v + q;
        int grc = min(max(gr, 0), IMG_H - 1);
        v[q] = img[(size_t)grc * IMG_W + gcc];
      }
      #pragma unroll
      for (int q = 0; q < 8; ++q) {
        int r2 = R0v + q;
        if (r2 < MW) {
          float acc = 0.f;
          #pragma unroll
          for (int j = 0; j < 11; ++j) acc = fmaf(g[j], win[q + j], acc);
          int gr = r0 - 5 + r2;
          bool in = (gr >= 0) && (gr < IMG_H) && (gc >= 0) && (gc < IMG_W);
          vmin = fminf(vmin, in ? v[q] : 1e30f);
          vmax = fmaxf(vmax, in ? v[q] : -1e30f);
          M[r2 * MST + cc] = in ? (v[q] - acc) : 0.f;
        }
      }
    }
  }
  __syncthreads();  // M1,M2 ready; S free

  // phase 2.5: inner mu in registers: mu = img - d (img reads are L2-hot)
  const int c_own = tid & 31;
  const int R0o = (tid >> 5) * 4;
  float mu1r[4], mu2r[4];
  #pragma unroll
  for (int k = 0; k < 4; ++k) {
    size_t off = (size_t)(r0 + R0o + k) * IMG_W + (c0 + c_own);
    mu1r[k] = i1[off] - M1[(R0o + k + 5) * MST + c_own + 5];
    mu2r[k] = i2[off] - M2[(R0o + k + 5) * MST + c_own + 5];
  }

  // merged stat pass: product + h-blur for all three stats -> 3 HP planes
  #pragma unroll
  for (int k = 0; k < 2; ++k) {
    unsigned idx = (unsigned)tid + 256u * k;
    if (idx < (unsigned)(MW * 8)) {
      unsigned i = idx >> 3;
      int oc0 = (int)(idx & 7u) * 4;
      float a[16], b[16];
      {
        const float4* p = (const float4*)&M1[i * MST + oc0];
        #pragma unroll
        for (int q = 0; q < 4; ++q) {
          float4 t = p[q];
          a[4 * q] = t.x; a[4 * q + 1] = t.y; a[4 * q + 2] = t.z; a[4 * q + 3] = t.w;
        }
      }
      {
        const float4* p = (const float4*)&M2[i * MST + oc0];
        #pragma unroll
        for (int q = 0; q < 4; ++q) {
          float4 t = p[q];
          b[4 * q] = t.x; b[4 * q + 1] = t.y; b[4 * q + 2] = t.z; b[4 * q + 3] = t.w;
        }
      }
      #pragma unroll
      for (int p = 0; p < 3; ++p) {
        float w[14];
        #pragma unroll
        for (int q = 0; q < 14; ++q)
          w[q] = (p == 0) ? a[q] * a[q] : (p == 1) ? b[q] * b[q] : a[q] * b[q];
        float4 o;
        float oq[4];
        #pragma unroll
        for (int q = 0; q < 4; ++q) {
          float acc = 0.f;
          #pragma unroll
          for (int j = 0; j < 11; ++j) acc = fmaf(g[j], w[q + j], acc);
          oq[q] = acc;
        }
        o.x = oq[0]; o.y = oq[1]; o.z = oq[2]; o.w = oq[3];
        *(float4*)&S[p * HPP + i * HPW + oc0] = o;
      }
    }
  }
  __syncthreads();

  // v-blur of the 3 HP planes -> per-thread stats (4 px/thread)
  float s11r[4], s22r[4], s12r[4];
  #pragma unroll
  for (int p = 0; p < 3; ++p) {
    float win[14];
    #pragma unroll
    for (int j = 0; j < 14; ++j) win[j] = S[p * HPP + (R0o + j) * HPW + c_own];
    #pragma unroll
    for (int k = 0; k < 4; ++k) {
      float acc = 0.f;
      #pragma unroll
      for (int j = 0; j < 11; ++j) acc = fmaf(g[j], win[k + j], acc);
      if (p == 0) s11r[k] = acc; else if (p == 1) s22r[k] = acc; else s12r[k] = acc;
    }
  }

  // combine: ssim ~= S0*B0 + C1*(S0*B') + C2*(B0*S')
  float acc0 = 0.f, aC1 = 0.f, aC2 = 0.f;
  #pragma unroll
  for (int k = 0; k < 4; ++k) {
    float s1 = s11r[k] + 1.f;
    float s2 = s22r[k] + 1.f;
    float s12v = s12r[k] + 1.f;
    float m1 = mu1r[k], m2 = mu2r[k];
    float a = 2.f * s12v;
    float b = s1 + s2;
    float rb = __builtin_amdgcn_rcpf(b);
    float S0 = a * rb;
    float Sp = (b - a) * rb * rb;
    float m12 = fmaf(m1, m2, 1.f);
    float nb = 2.f * m12;
    float N1 = nb * nb;
    float ms = fmaf(m1, m1, fmaf(m2, m2, 2.f));
    float D1 = ms * ms;
    float rD = __builtin_amdgcn_rcpf(D1);
    float B0 = N1 * rD;
    float Bp = (D1 - N1) * rD * rD;
    acc0 = fmaf(S0, B0, acc0);
    aC1 = fmaf(S0, Bp, aC1);
    aC2 = fmaf(B0, Sp, aC2);
  }

  // block reduction
  #pragma unroll
  for (int off = 32; off > 0; off >>= 1) {
    acc0 += __shfl_down(acc0, off);
    aC1 += __shfl_down(aC1, off);
    aC2 += __shfl_down(aC2, off);
    vmin = fminf(vmin, __shfl_down(vmin, off));
    vmax = fmaxf(vmax, __shfl_down(vmax, off));
  }
  const int wv = tid >> 6, ln = tid & 63;
  if (ln == 0) {
    redbuf[wv][0] = acc0; redbuf[wv][1] = aC1; redbuf[wv][2] = aC2;
    redbuf[wv][3] = vmin; redbuf[wv][4] = vmax;
  }
  __syncthreads();
  if (tid == 0) {
    float t0 = 0.f, t1 = 0.f, t2 = 0.f, mn = 1e30f, mx = -1e30f;
    #pragma unroll
    for (int w2 = 0; w2 < 4; ++w2) {
      t0 += redbuf[w2][0]; t1 += redbuf[w2][1]; t2 += redbuf[w2][2];
      mn = fminf(mn, redbuf[w2][3]); mx = fmaxf(mx, redbuf[w2][4]);
    }
    unsigned slot = (blockIdx.x + blockIdx.y * 32u + blockIdx.z * 7u) & (NSLOT - 1);
    float* wsF = (float*)ws;
    atomicAdd(&wsF[slot * 8 + 0], t0);
    atomicAdd(&wsF[slot * 8 + 1], t1);
    atomicAdd(&wsF[slot * 8 + 2], t2);
    atomicMax(&ws[slot * 8 + 3], fkey(-mn));  // min via negation; 0-init valid
    atomicMax(&ws[slot * 8 + 4], fkey(mx));   // fkey(real) > 0 always
  }
}

__global__ void ssim_final(const unsigned* __restrict__ ws, float* __restrict__ out) {
  const int t = threadIdx.x;  // 64 threads, one wave
  const float* wsF = (const float*)ws;
  float t0 = wsF[t * 8 + 0], t1 = wsF[t * 8 + 1], t2 = wsF[t * 8 + 2];
  unsigned kmn = ws[t * 8 + 3], kmx = ws[t * 8 + 4];
  #pragma unroll
  for (int off = 32; off > 0; off >>= 1) {
    t0 += __shfl_down(t0, off);
    t1 += __shfl_down(t1, off);
    t2 += __shfl_down(t2, off);
    kmn = max(kmn, (unsigned)__shfl_down((int)kmn, off));
    kmx = max(kmx, (unsigned)__shfl_down((int)kmx, off));
  }
  if (t == 0) {
    float mn = -funkey(kmn), mx = funkey(kmx);
    float vr = mx - mn + 1e-5f;
    float c1 = 0.01f * vr; c1 *= c1;
    float c2 = 0.03f * vr; c2 *= c2;
    float mean = (t0 + c1 * t1 + c2 * t2) * (1.0f / 16777216.0f);
    out[0] = 1.f - mean;
  }
}

extern "C" void kernel_launch(void* const* d_in, const int* in_sizes, int n_in,
                              void* d_out, int out_size, void* d_ws, size_t ws_size,
                              hipStream_t stream) {
  const float* img1 = (const float*)d_in[0];
  const float* img2 = (const float*)d_in[1];
  const float* kern = (const float*)d_in[2];
  unsigned* ws = (unsigned*)d_ws;
  float* out = (float*)d_out;
  (void)in_sizes; (void)n_in; (void)out_size; (void)ws_size;

  hipMemsetAsync(ws, 0, NSLOT * 8 * sizeof(unsigned), stream);
  hipLaunchKernelGGL(ssim_main, dim3(IMG_W / TS, IMG_H / TS, 16), dim3(256), 0,
                     stream, img1, img2, kern, ws);
  hipLaunchKernelGGL(ssim_final, dim3(1), dim3(NSLOT), 0, stream, ws, out);
}